// Round 2
// baseline (2079.018 us; speedup 1.0000x reference)
//
#include <hip/hip_runtime.h>

// MHA block: out = (softmax(QK^T/sqrt(dk)) V) @ Wo^T, Q/K/V = x @ W^T
// B=2, S=2048, HIDDEN=4096, HEADS=32, DK=128. All fp32 in/out, bf16 MFMA inside.

typedef __attribute__((ext_vector_type(8))) short bf16x8;
typedef __attribute__((ext_vector_type(4))) float f32x4;

__device__ __forceinline__ unsigned short f2bf(float f) {
  unsigned int u = __float_as_uint(f);
  unsigned int r = (u + 0x7fffu + ((u >> 16) & 1u)) >> 16;
  return (unsigned short)r;
}

__device__ __forceinline__ void gload_lds16(const void* g, void* l) {
  __builtin_amdgcn_global_load_lds(
      (__attribute__((address_space(1))) void*)(g),
      (__attribute__((address_space(3))) void*)(l), 16, 0, 0);
}

// ---------------- fp32 -> bf16 convert (vectorized) ----------------
__global__ void mha_f32_to_bf16(const float* __restrict__ in,
                                unsigned short* __restrict__ out, int n4) {
  int i = blockIdx.x * 256 + threadIdx.x;
  if (i >= n4) return;
  float4 v = reinterpret_cast<const float4*>(in)[i];
  ushort4 o;
  o.x = f2bf(v.x); o.y = f2bf(v.y); o.z = f2bf(v.z); o.w = f2bf(v.w);
  reinterpret_cast<ushort4*>(out)[i] = o;
}

// ---------------- bf16 bt-GEMM: C[M,N] = A[M,K] @ B[N,K]^T ----------------
template<int BF16OUT>
__global__ __launch_bounds__(256) void mha_gemm_bt(
    const unsigned short* __restrict__ A,
    const unsigned short* __restrict__ B,
    void* __restrict__ Cout, int M, int N, int K) {
  __shared__ __align__(16) unsigned short As[128 * 32];
  __shared__ __align__(16) unsigned short Bs[128 * 32];
  const int tid = threadIdx.x;
  const int lane = tid & 63;
  const int wid = tid >> 6;
  const int wm = wid >> 1, wn = wid & 1;
  const int bm = blockIdx.x, bn = blockIdx.y;

  const unsigned short* Ab = A + (size_t)bm * 128 * K;
  const unsigned short* Bb = B + (size_t)bn * 128 * K;

  const int ca = wid * 2;
  const int rowA0 = ca * 16 + (lane >> 2);
  const int kcol = (lane & 3) * 8;

  f32x4 acc[4][4] = {};

  for (int k0 = 0; k0 < K; k0 += 32) {
    __syncthreads();
    gload_lds16(Ab + (size_t)rowA0 * K + k0 + kcol, (char*)As + ca * 1024);
    gload_lds16(Ab + (size_t)(rowA0 + 16) * K + k0 + kcol, (char*)As + ca * 1024 + 1024);
    gload_lds16(Bb + (size_t)rowA0 * K + k0 + kcol, (char*)Bs + ca * 1024);
    gload_lds16(Bb + (size_t)(rowA0 + 16) * K + k0 + kcol, (char*)Bs + ca * 1024 + 1024);
    __syncthreads();
    bf16x8 a[4], b[4];
#pragma unroll
    for (int i = 0; i < 4; ++i) {
      a[i] = *reinterpret_cast<const bf16x8*>(&As[(wm * 64 + i * 16 + (lane & 15)) * 32 + (lane >> 4) * 8]);
      b[i] = *reinterpret_cast<const bf16x8*>(&Bs[(wn * 64 + i * 16 + (lane & 15)) * 32 + (lane >> 4) * 8]);
    }
#pragma unroll
    for (int i = 0; i < 4; ++i)
#pragma unroll
      for (int j = 0; j < 4; ++j)
        acc[i][j] = __builtin_amdgcn_mfma_f32_16x16x32_bf16(a[i], b[j], acc[i][j], 0, 0, 0);
  }

  const int r0 = bm * 128 + wm * 64 + (lane >> 4) * 4;
  const int c0 = bn * 128 + wn * 64 + (lane & 15);
#pragma unroll
  for (int i = 0; i < 4; ++i)
#pragma unroll
    for (int j = 0; j < 4; ++j)
#pragma unroll
      for (int r = 0; r < 4; ++r) {
        size_t idx = (size_t)(r0 + i * 16 + r) * N + (c0 + j * 16);
        if (BF16OUT) ((unsigned short*)Cout)[idx] = f2bf(acc[i][j][r]);
        else ((float*)Cout)[idx] = acc[i][j][r];
      }
}

// ---------------- V transpose: vt[b][h][d][s] <- v[(b*S+s)][h*128+d] ----------------
// grid (S/64, B*H*2), block 256. LDS tile [64][66] (pad 66 breaks column conflicts).
__global__ __launch_bounds__(256) void mha_vtrans(
    const unsigned short* __restrict__ vb, unsigned short* __restrict__ vt) {
  const int S = 2048, HID = 4096;
  const int st = blockIdx.x;
  const int y = blockIdx.y;
  const int dt = y & 1;
  const int bh = y >> 1;
  const int b = bh >> 5;
  const int h = bh & 31;
  __shared__ unsigned short T[64 * 66];
  const int t = threadIdx.x;

#pragma unroll
  for (int p = 0; p < 2; ++p) {
    int si = p * 32 + (t >> 3);
    int dj = t & 7;
    bf16x8 v = *reinterpret_cast<const bf16x8*>(
        vb + ((size_t)(b * S) + st * 64 + si) * HID + h * 128 + dt * 64 + dj * 8);
#pragma unroll
    for (int k = 0; k < 4; ++k) {
      unsigned int u = (unsigned int)(unsigned short)v[2 * k] |
                       ((unsigned int)(unsigned short)v[2 * k + 1] << 16);
      *reinterpret_cast<unsigned int*>((char*)T + si * 132 + dj * 16 + k * 4) = u;
    }
  }
  __syncthreads();
#pragma unroll
  for (int p = 0; p < 2; ++p) {
    int dd = p * 32 + (t >> 3);
    int sj = t & 7;
    bf16x8 o;
#pragma unroll
    for (int i = 0; i < 8; ++i)
      o[i] = (short)T[(sj * 8 + i) * 66 + dd];
    *reinterpret_cast<bf16x8*>(
        vt + ((size_t)bh * 128 + dt * 64 + dd) * S + st * 64 + sj * 8) = o;
  }
}

// ---------------- flash attention (no K/V LDS staging; L2-direct fragments) ----------------
// Q,K in [B*S, 4096] bf16; Vt in [B*H][128][S] bf16. grid = 2048 1-D (XCD-chunk swizzled).
__global__ __launch_bounds__(256) void mha_flash(
    const unsigned short* __restrict__ Q, const unsigned short* __restrict__ K,
    const unsigned short* __restrict__ Vt, unsigned short* __restrict__ O) {
  const int S = 2048, HID = 4096;
  // bijective XCD-chunk swizzle: XCD x gets heads [8x, 8x+8), q-tiles sequential
  const int orig = blockIdx.x;
  const int swz = (orig & 7) * 256 + (orig >> 3);
  const int qt = swz & 31;
  const int bh = swz >> 5;
  const int b = bh >> 5, h = bh & 31;
  const int q0 = qt * 64;
  const int tid = threadIdx.x, lane = tid & 63, w = tid >> 6;
  const int l = lane & 15, g = lane >> 4;

  __shared__ __align__(16) unsigned short Ps[4][16 * 64]; // per-wave P tile, XOR-swizzled

  const unsigned short* qbase = Q + (size_t)(b * S) * HID + h * 128;
  const unsigned short* kbase = K + (size_t)(b * S) * HID + h * 128;
  const unsigned short* vtbase = Vt + (size_t)bh * 128 * S;

  // Q fragments in registers: row = q0 + w*16 + l, k = ks*32 + g*8
  bf16x8 qf[4];
#pragma unroll
  for (int ks = 0; ks < 4; ++ks)
    qf[ks] = *reinterpret_cast<const bf16x8*>(
        qbase + (size_t)(q0 + w * 16 + l) * HID + ks * 32 + g * 8);

  float mrow[4] = {-INFINITY, -INFINITY, -INFINITY, -INFINITY};
  float lrow[4] = {0.f, 0.f, 0.f, 0.f};
  f32x4 o[8] = {};
  const float scale = 0.08838834764831843f; // 1/sqrt(128)

  for (int kt = 0; kt < S / 64; ++kt) {
    // S_tile[16q][64k] = Q @ K^T, K fragments direct from global (L2-resident)
    f32x4 sacc[4] = {};
#pragma unroll
    for (int cf = 0; cf < 4; ++cf)
#pragma unroll
      for (int ks = 0; ks < 4; ++ks) {
        bf16x8 kf = *reinterpret_cast<const bf16x8*>(
            kbase + (size_t)(kt * 64 + cf * 16 + l) * HID + ks * 32 + g * 8);
        sacc[cf] = __builtin_amdgcn_mfma_f32_16x16x32_bf16(qf[ks], kf, sacc[cf], 0, 0, 0);
      }
#pragma unroll
    for (int cf = 0; cf < 4; ++cf)
#pragma unroll
      for (int r = 0; r < 4; ++r)
        sacc[cf][r] *= scale;

    // online softmax; acc row = g*4 + r, cols spread over 16 lanes x 4 frags
#pragma unroll
    for (int r = 0; r < 4; ++r) {
      float mx = fmaxf(fmaxf(sacc[0][r], sacc[1][r]), fmaxf(sacc[2][r], sacc[3][r]));
#pragma unroll
      for (int d = 1; d < 16; d <<= 1) mx = fmaxf(mx, __shfl_xor(mx, d, 64));
      float mn = fmaxf(mrow[r], mx);
      float sc = __expf(mrow[r] - mn);
      float rs = 0.f;
#pragma unroll
      for (int cf = 0; cf < 4; ++cf) {
        float p = __expf(sacc[cf][r] - mn);
        sacc[cf][r] = p;
        rs += p;
      }
#pragma unroll
      for (int d = 1; d < 16; d <<= 1) rs += __shfl_xor(rs, d, 64);
      mrow[r] = mn;
      lrow[r] = lrow[r] * sc + rs;
#pragma unroll
      for (int df = 0; df < 8; ++df) o[df][r] *= sc;
    }

    // P -> LDS bf16, XOR-swizzled (byte ^= (row&7)<<4); wave-private, no barrier
#pragma unroll
    for (int cf = 0; cf < 4; ++cf)
#pragma unroll
      for (int r = 0; r < 4; ++r) {
        int row = g * 4 + r;
        int boff = (row * 128 + (cf * 16 + l) * 2) ^ ((row & 7) << 4);
        *reinterpret_cast<unsigned short*>((char*)Ps[w] + boff) = f2bf(sacc[cf][r]);
      }

    // O[16q][128d] += P @ V ; V^T fragments direct from global
#pragma unroll
    for (int kk = 0; kk < 2; ++kk) {
      int prow = l;
      int pboff = (prow * 128 + (kk * 32 + g * 8) * 2) ^ ((prow & 7) << 4);
      bf16x8 pf = *reinterpret_cast<const bf16x8*>((char*)Ps[w] + pboff);
#pragma unroll
      for (int df = 0; df < 8; ++df) {
        bf16x8 vf = *reinterpret_cast<const bf16x8*>(
            vtbase + (size_t)(df * 16 + l) * S + kt * 64 + kk * 32 + g * 8);
        o[df] = __builtin_amdgcn_mfma_f32_16x16x32_bf16(pf, vf, o[df], 0, 0, 0);
      }
    }
  }

  // epilogue: O /= l, write bf16 [B*S][4096]
#pragma unroll
  for (int r = 0; r < 4; ++r) {
    float inv = 1.f / lrow[r];
    int row = q0 + w * 16 + g * 4 + r;
    unsigned short* ob = O + (size_t)(b * S + row) * HID + h * 128;
#pragma unroll
    for (int df = 0; df < 8; ++df)
      ob[df * 16 + l] = f2bf(o[df][r] * inv);
  }
}

// ---------------- launch ----------------
extern "C" void kernel_launch(void* const* d_in, const int* in_sizes, int n_in,
                              void* d_out, int out_size, void* d_ws, size_t ws_size,
                              hipStream_t stream) {
  const float* x = (const float*)d_in[0];
  const float* wq = (const float*)d_in[1];
  const float* wk = (const float*)d_in[2];
  const float* wv = (const float*)d_in[3];
  const float* wo = (const float*)d_in[4];
  float* out = (float*)d_out;

  const size_t E = 16777216; // 4096*4096
  // ws (bf16): [xb | wb | qb | kb | vb] = 160 MB
  unsigned short* xb = (unsigned short*)d_ws;
  unsigned short* wb = xb + E;      // weights; later holds V^T
  unsigned short* qb = xb + 2 * E;
  unsigned short* kb = xb + 3 * E;
  unsigned short* vb = xb + 4 * E;  // V; later holds Wo bf16
  unsigned short* ab = xb;          // attn-out reuses xb

  dim3 cb(256);
  dim3 cg((unsigned)(E / 4 / 256));
  dim3 gg(32, 32), gb(256);

  mha_f32_to_bf16<<<cg, cb, 0, stream>>>(x, xb, (int)(E / 4));
  mha_f32_to_bf16<<<cg, cb, 0, stream>>>(wq, wb, (int)(E / 4));
  mha_gemm_bt<1><<<gg, gb, 0, stream>>>(xb, wb, (void*)qb, 4096, 4096, 4096);
  mha_f32_to_bf16<<<cg, cb, 0, stream>>>(wk, wb, (int)(E / 4));
  mha_gemm_bt<1><<<gg, gb, 0, stream>>>(xb, wb, (void*)kb, 4096, 4096, 4096);
  mha_f32_to_bf16<<<cg, cb, 0, stream>>>(wv, wb, (int)(E / 4));
  mha_gemm_bt<1><<<gg, gb, 0, stream>>>(xb, wb, (void*)vb, 4096, 4096, 4096);
  mha_vtrans<<<dim3(32, 128), cb, 0, stream>>>(vb, wb);      // V^T into wb
  mha_flash<<<dim3(2048), cb, 0, stream>>>(qb, kb, wb, ab);  // attn-out into xb
  mha_f32_to_bf16<<<cg, cb, 0, stream>>>(wo, vb, (int)(E / 4)); // Wo bf16 into vb
  mha_gemm_bt<0><<<gg, gb, 0, stream>>>(ab, vb, (void*)out, 4096, 4096, 4096);
}

// Round 4
// 1605.798 us; speedup vs baseline: 1.2947x; 1.2947x over previous
//
#include <hip/hip_runtime.h>

// MHA block: out = (softmax(QK^T/sqrt(dk)) V) @ Wo^T, Q/K/V = x @ W^T
// B=2, S=2048, HIDDEN=4096, HEADS=32, DK=128. All fp32 in/out, bf16 MFMA inside.

typedef __attribute__((ext_vector_type(8))) short bf16x8;
typedef __attribute__((ext_vector_type(4))) float f32x4;
typedef __attribute__((ext_vector_type(16))) float f32x16;

__device__ __forceinline__ unsigned short f2bf(float f) {
  unsigned int u = __float_as_uint(f);
  unsigned int r = (u + 0x7fffu + ((u >> 16) & 1u)) >> 16;
  return (unsigned short)r;
}

__device__ __forceinline__ void gload_lds16(const void* g, void* l) {
  __builtin_amdgcn_global_load_lds(
      (__attribute__((address_space(1))) void*)(g),
      (__attribute__((address_space(3))) void*)(l), 16, 0, 0);
}

// ---------------- fp32 -> bf16 convert (vectorized) ----------------
__global__ void mha_f32_to_bf16(const float* __restrict__ in,
                                unsigned short* __restrict__ out, int n4) {
  int i = blockIdx.x * 256 + threadIdx.x;
  if (i >= n4) return;
  float4 v = reinterpret_cast<const float4*>(in)[i];
  ushort4 o;
  o.x = f2bf(v.x); o.y = f2bf(v.y); o.z = f2bf(v.z); o.w = f2bf(v.w);
  reinterpret_cast<ushort4*>(out)[i] = o;
}

// ---------------- bf16 bt-GEMM: C[M,N] = A[M,K] @ B[N,K]^T ----------------
template<int BF16OUT>
__global__ __launch_bounds__(256) void mha_gemm_bt(
    const unsigned short* __restrict__ A,
    const unsigned short* __restrict__ B,
    void* __restrict__ Cout, int M, int N, int K) {
  __shared__ __align__(16) unsigned short As[128 * 32];
  __shared__ __align__(16) unsigned short Bs[128 * 32];
  const int tid = threadIdx.x;
  const int lane = tid & 63;
  const int wid = tid >> 6;
  const int wm = wid >> 1, wn = wid & 1;
  const int bm = blockIdx.x, bn = blockIdx.y;

  const unsigned short* Ab = A + (size_t)bm * 128 * K;
  const unsigned short* Bb = B + (size_t)bn * 128 * K;

  const int ca = wid * 2;
  const int rowA0 = ca * 16 + (lane >> 2);
  const int kcol = (lane & 3) * 8;

  f32x4 acc[4][4] = {};

  for (int k0 = 0; k0 < K; k0 += 32) {
    __syncthreads();
    gload_lds16(Ab + (size_t)rowA0 * K + k0 + kcol, (char*)As + ca * 1024);
    gload_lds16(Ab + (size_t)(rowA0 + 16) * K + k0 + kcol, (char*)As + ca * 1024 + 1024);
    gload_lds16(Bb + (size_t)rowA0 * K + k0 + kcol, (char*)Bs + ca * 1024);
    gload_lds16(Bb + (size_t)(rowA0 + 16) * K + k0 + kcol, (char*)Bs + ca * 1024 + 1024);
    __syncthreads();
    bf16x8 a[4], b[4];
#pragma unroll
    for (int i = 0; i < 4; ++i) {
      a[i] = *reinterpret_cast<const bf16x8*>(&As[(wm * 64 + i * 16 + (lane & 15)) * 32 + (lane >> 4) * 8]);
      b[i] = *reinterpret_cast<const bf16x8*>(&Bs[(wn * 64 + i * 16 + (lane & 15)) * 32 + (lane >> 4) * 8]);
    }
#pragma unroll
    for (int i = 0; i < 4; ++i)
#pragma unroll
      for (int j = 0; j < 4; ++j)
        acc[i][j] = __builtin_amdgcn_mfma_f32_16x16x32_bf16(a[i], b[j], acc[i][j], 0, 0, 0);
  }

  const int r0 = bm * 128 + wm * 64 + (lane >> 4) * 4;
  const int c0 = bn * 128 + wn * 64 + (lane & 15);
#pragma unroll
  for (int i = 0; i < 4; ++i)
#pragma unroll
    for (int j = 0; j < 4; ++j)
#pragma unroll
      for (int r = 0; r < 4; ++r) {
        size_t idx = (size_t)(r0 + i * 16 + r) * N + (c0 + j * 16);
        if (BF16OUT) ((unsigned short*)Cout)[idx] = f2bf(acc[i][j][r]);
        else ((float*)Cout)[idx] = acc[i][j][r];
      }
}

// ---------------- V transpose: vt[b][h][d][s] <- v[(b*S+s)][h*128+d] ----------------
__global__ __launch_bounds__(256) void mha_vtrans(
    const unsigned short* __restrict__ vb, unsigned short* __restrict__ vt) {
  const int S = 2048, HID = 4096;
  const int st = blockIdx.x;
  const int y = blockIdx.y;
  const int dt = y & 1;
  const int bh = y >> 1;
  const int b = bh >> 5;
  const int h = bh & 31;
  __shared__ unsigned short T[64 * 66];
  const int t = threadIdx.x;

#pragma unroll
  for (int p = 0; p < 2; ++p) {
    int si = p * 32 + (t >> 3);
    int dj = t & 7;
    bf16x8 v = *reinterpret_cast<const bf16x8*>(
        vb + ((size_t)(b * S) + st * 64 + si) * HID + h * 128 + dt * 64 + dj * 8);
#pragma unroll
    for (int k = 0; k < 4; ++k) {
      unsigned int u = (unsigned int)(unsigned short)v[2 * k] |
                       ((unsigned int)(unsigned short)v[2 * k + 1] << 16);
      *reinterpret_cast<unsigned int*>((char*)T + si * 132 + dj * 16 + k * 4) = u;
    }
  }
  __syncthreads();
#pragma unroll
  for (int p = 0; p < 2; ++p) {
    int dd = p * 32 + (t >> 3);
    int sj = t & 7;
    bf16x8 o;
#pragma unroll
    for (int i = 0; i < 8; ++i)
      o[i] = (short)T[(sj * 8 + i) * 66 + dd];
    *reinterpret_cast<bf16x8*>(
        vt + ((size_t)bh * 128 + dt * 64 + dd) * S + st * 64 + sj * 8) = o;
  }
}

// ---------------- flash attention, swapped-QK^T 32x32 in-register softmax ----------------
// Q,K in [B*S, 4096] bf16; Vt in [B*H][128][S] bf16. grid = 1024 (XCD-chunk swizzled).
// 4 waves/block, each wave owns 32 q-rows (q = lane&31). No LDS, no barriers.
__global__ __launch_bounds__(256, 2) void mha_flash(
    const unsigned short* __restrict__ Q, const unsigned short* __restrict__ K,
    const unsigned short* __restrict__ Vt, unsigned short* __restrict__ O) {
  const int S = 2048, HID = 4096;
  const int orig = blockIdx.x;                    // 1024 blocks, 1024%8==0 -> bijective
  const int swz = (orig & 7) * 128 + (orig >> 3); // XCD x: contiguous chunk of 128
  const int qt = swz & 15;                        // 16 q-tiles of 128 rows
  const int bh = swz >> 4;                        // head-major within chunk
  const int b = bh >> 5, h = bh & 31;
  const int tid = threadIdx.x, lane = tid & 63, w = tid >> 6;
  const int ql = lane & 31; // q col / kv row / d row index within 32-tile
  const int g = lane >> 5;  // half-wave

  const unsigned short* qbase = Q + (size_t)(b * S) * HID + h * 128;
  const unsigned short* kbase = K + (size_t)(b * S) * HID + h * 128;
  const unsigned short* vtbase = Vt + (size_t)bh * 128 * S;

  const int qrow = qt * 128 + w * 32 + ql;

  // Q regs (B-operand: lane n=q, k-slice d = st*16 + g*8 + e)
  bf16x8 qf[8];
#pragma unroll
  for (int st = 0; st < 8; ++st)
    qf[st] = *reinterpret_cast<const bf16x8*>(qbase + (size_t)qrow * HID + st * 16 + g * 8);

  float m2 = -INFINITY;  // running max, in exp2-units (raw*scale*log2e)
  float lsumT = 0.f;     // running denom
  f32x16 oacc[4] = {};   // O^T: col q = lane&31, rows d = dt*32 + (r&3)+8*(r>>2)+4g
  const float cexp = 0.08838834764831843f * 1.44269504088896341f; // 1/sqrt(128)*log2(e)

  for (int kt = 0; kt < 32; ++kt) {
    const int kv0 = kt * 64;
    // --- S^T[kv][q] = K @ Q^T via swapped mfma(A=K, B=Q) ---
    f32x16 sa0 = {}, sa1 = {};
#pragma unroll
    for (int st = 0; st < 8; ++st) {
      bf16x8 kf = *reinterpret_cast<const bf16x8*>(
          kbase + (size_t)(kv0 + ql) * HID + st * 16 + g * 8);
      sa0 = __builtin_amdgcn_mfma_f32_32x32x16_bf16(kf, qf[st], sa0, 0, 0, 0);
    }
#pragma unroll
    for (int st = 0; st < 8; ++st) {
      bf16x8 kf = *reinterpret_cast<const bf16x8*>(
          kbase + (size_t)(kv0 + 32 + ql) * HID + st * 16 + g * 8);
      sa1 = __builtin_amdgcn_mfma_f32_32x32x16_bf16(kf, qf[st], sa1, 0, 0, 0);
    }

    // --- in-lane row max over 32 values + one cross-half exchange ---
    float pm = sa0[0];
#pragma unroll
    for (int r = 1; r < 16; ++r) pm = fmaxf(pm, sa0[r]);
#pragma unroll
    for (int r = 0; r < 16; ++r) pm = fmaxf(pm, sa1[r]);
    pm = fmaxf(pm, __shfl_xor(pm, 32, 64));
    float pm2 = pm * cexp;

    // --- T13 defer-max: rescale only if some lane's max grew by >8 ---
    if (__any((pm2 - m2 > 8.f) ? 1 : 0)) {
      float mn = fmaxf(m2, pm2);
      float sc = exp2f(m2 - mn);
      m2 = mn;
      lsumT *= sc;
#pragma unroll
      for (int dt = 0; dt < 4; ++dt)
#pragma unroll
        for (int r = 0; r < 16; ++r) oacc[dt][r] *= sc;
    }

    // --- P = exp2(s*cexp - m2), in-lane sum ---
    float ls = 0.f;
#pragma unroll
    for (int r = 0; r < 16; ++r) {
      float p = exp2f(fmaf(sa0[r], cexp, -m2)); sa0[r] = p; ls += p;
    }
#pragma unroll
    for (int r = 0; r < 16; ++r) {
      float p = exp2f(fmaf(sa1[r], cexp, -m2)); sa1[r] = p; ls += p;
    }
    lsumT += ls + __shfl_xor(ls, 32, 64);

    // --- T12: P -> bf16 B-fragments in-register (cvt_pk + permlane32_swap) ---
    // window wdw covers kv-local [wdw*16, wdw*16+16); uses regs rb..rb+7 of sa(sub)
#pragma unroll
    for (int wdw = 0; wdw < 4; ++wdw) {
      const f32x16& ps = (wdw < 2) ? sa0 : sa1;
      const int rb = (wdw & 1) * 8;
      unsigned int a1, b1, a2, b2;
      asm("v_cvt_pk_bf16_f32 %0, %1, %2" : "=v"(a1) : "v"(ps[rb + 0]), "v"(ps[rb + 1]));
      asm("v_cvt_pk_bf16_f32 %0, %1, %2" : "=v"(b1) : "v"(ps[rb + 4]), "v"(ps[rb + 5]));
      asm("v_cvt_pk_bf16_f32 %0, %1, %2" : "=v"(a2) : "v"(ps[rb + 2]), "v"(ps[rb + 3]));
      asm("v_cvt_pk_bf16_f32 %0, %1, %2" : "=v"(b2) : "v"(ps[rb + 6]), "v"(ps[rb + 7]));
      // D_new = (D_lo, S_lo), S_new = (D_hi, S_hi)
      asm("v_permlane32_swap_b32 %0, %1" : "+v"(a1), "+v"(b1));
      asm("v_permlane32_swap_b32 %0, %1" : "+v"(a2), "+v"(b2));
      union { unsigned int u[4]; bf16x8 v; } pb;
      pb.u[0] = a1; pb.u[1] = a2; pb.u[2] = b1; pb.u[3] = b2;
      // --- PV: O^T += V^T @ P^T ---
#pragma unroll
      for (int dt = 0; dt < 4; ++dt) {
        bf16x8 vf = *reinterpret_cast<const bf16x8*>(
            vtbase + (size_t)(dt * 32 + ql) * S + kv0 + wdw * 16 + g * 8);
        oacc[dt] = __builtin_amdgcn_mfma_f32_32x32x16_bf16(vf, pb.v, oacc[dt], 0, 0, 0);
      }
    }
  }

  // --- epilogue: out[q][d] = O^T[d][q] / l ; paired u32 stores ---
  const float inv = 1.f / lsumT;
  unsigned short* ob = O + (size_t)(b * S + qrow) * HID + h * 128;
#pragma unroll
  for (int dt = 0; dt < 4; ++dt)
#pragma unroll
    for (int q2 = 0; q2 < 4; ++q2)
#pragma unroll
      for (int e = 0; e < 2; ++e) {
        int r = q2 * 4 + e * 2;
        int d = dt * 32 + e * 2 + 8 * q2 + 4 * g;
        unsigned int u = (unsigned int)f2bf(oacc[dt][r] * inv) |
                         ((unsigned int)f2bf(oacc[dt][r + 1] * inv) << 16);
        *reinterpret_cast<unsigned int*>(ob + d) = u;
      }
}

// ---------------- launch ----------------
extern "C" void kernel_launch(void* const* d_in, const int* in_sizes, int n_in,
                              void* d_out, int out_size, void* d_ws, size_t ws_size,
                              hipStream_t stream) {
  const float* x = (const float*)d_in[0];
  const float* wq = (const float*)d_in[1];
  const float* wk = (const float*)d_in[2];
  const float* wv = (const float*)d_in[3];
  const float* wo = (const float*)d_in[4];
  float* out = (float*)d_out;

  const size_t E = 16777216; // 4096*4096
  unsigned short* xb = (unsigned short*)d_ws;
  unsigned short* wb = xb + E;      // weights; later holds V^T
  unsigned short* qb = xb + 2 * E;
  unsigned short* kb = xb + 3 * E;
  unsigned short* vb = xb + 4 * E;  // V; later holds Wo bf16
  unsigned short* ab = xb;          // attn-out reuses xb

  dim3 cb(256);
  dim3 cg((unsigned)(E / 4 / 256));
  dim3 gg(32, 32), gb(256);

  mha_f32_to_bf16<<<cg, cb, 0, stream>>>(x, xb, (int)(E / 4));
  mha_f32_to_bf16<<<cg, cb, 0, stream>>>(wq, wb, (int)(E / 4));
  mha_gemm_bt<1><<<gg, gb, 0, stream>>>(xb, wb, (void*)qb, 4096, 4096, 4096);
  mha_f32_to_bf16<<<cg, cb, 0, stream>>>(wk, wb, (int)(E / 4));
  mha_gemm_bt<1><<<gg, gb, 0, stream>>>(xb, wb, (void*)kb, 4096, 4096, 4096);
  mha_f32_to_bf16<<<cg, cb, 0, stream>>>(wv, wb, (int)(E / 4));
  mha_gemm_bt<1><<<gg, gb, 0, stream>>>(xb, wb, (void*)vb, 4096, 4096, 4096);
  mha_vtrans<<<dim3(32, 128), cb, 0, stream>>>(vb, wb);         // V^T into wb
  mha_flash<<<dim3(1024), cb, 0, stream>>>(qb, kb, wb, ab);     // attn-out into xb
  mha_f32_to_bf16<<<cg, cb, 0, stream>>>(wo, vb, (int)(E / 4)); // Wo bf16 into vb
  mha_gemm_bt<0><<<gg, gb, 0, stream>>>(ab, vb, (void*)out, 4096, 4096, 4096);
}